// Round 1
// baseline (246.663 us; speedup 1.0000x reference)
//
#include <hip/hip_runtime.h>
#include <hip/hip_bf16.h>

#define N_NODES 50000
#define N_EDGES 150000
#define N_FACES 100000
#define NB 64      // graphs
#define NS 32      // thresholds
#define NT 32      // directions
#define SCALE_C 500.0f
#define CH 128     // simplices per block in accumulate

__device__ __forceinline__ float sigf(float z) {
    // sigmoid(z) = 1/(1+exp(-z)); saturates cleanly: exp(+inf)->inf, rcp(inf)->0
    float e = __expf(-z);
    return __builtin_amdgcn_rcpf(1.0f + e);
}

// ---------------- K1: node heights nh[n][t] = nw[n] * (x[n,:] . v[:,t]) ----
__global__ void nh_kernel(const float* __restrict__ x, const float* __restrict__ nw,
                          const float* __restrict__ v, float* __restrict__ nh) {
    int idx = blockIdx.x * blockDim.x + threadIdx.x;
    if (idx >= N_NODES * NT) return;
    int n = idx >> 5, t = idx & 31;
    float w = nw[n];
    float x0 = x[3 * n], x1 = x[3 * n + 1], x2 = x[3 * n + 2];
    float h = w * (x0 * v[t] + x1 * v[NT + t] + x2 * v[2 * NT + t]);
    nh[idx] = h;
}

// ---------------- K2: graph ids for edges/faces + per-graph histograms -----
__global__ void hist_kernel(const int* __restrict__ ei, const int* __restrict__ fi,
                            const int* __restrict__ batch,
                            int* __restrict__ ge, int* __restrict__ gf,
                            int* __restrict__ hist_e, int* __restrict__ hist_f) {
    __shared__ int he[NB], hf[NB];
    if (threadIdx.x < NB) { he[threadIdx.x] = 0; hf[threadIdx.x] = 0; }
    __syncthreads();
    int stride = gridDim.x * blockDim.x;
    for (int i = blockIdx.x * blockDim.x + threadIdx.x; i < N_EDGES; i += stride) {
        int g = batch[ei[i]];   // batch[edge_index[0]]
        ge[i] = g;
        atomicAdd(&he[g], 1);
    }
    for (int i = blockIdx.x * blockDim.x + threadIdx.x; i < N_FACES; i += stride) {
        int g = batch[fi[i]];   // batch[face[0]]
        gf[i] = g;
        atomicAdd(&hf[g], 1);
    }
    __syncthreads();
    if (threadIdx.x < NB) {
        if (he[threadIdx.x]) atomicAdd(&hist_e[threadIdx.x], he[threadIdx.x]);
        if (hf[threadIdx.x]) atomicAdd(&hist_f[threadIdx.x], hf[threadIdx.x]);
    }
}

// ---------------- K3: exclusive scan (64 bins, serial — trivial) -----------
__global__ void scan_kernel(const int* __restrict__ hist_e, const int* __restrict__ hist_f,
                            int* __restrict__ cur_e, int* __restrict__ cur_f) {
    if (threadIdx.x == 0) {
        int s = 0;
        for (int g = 0; g < NB; g++) { cur_e[g] = s; s += hist_e[g]; }
        s = 0;
        for (int g = 0; g < NB; g++) { cur_f[g] = s; s += hist_f[g]; }
    }
}

// ---------------- K4: two-level counting-sort scatter ----------------------
__global__ void scatter_kernel(const int* __restrict__ garr, int M,
                               int* __restrict__ cursors,
                               int* __restrict__ perm, int* __restrict__ gs) {
    __shared__ int cnt[NB], base[NB];
    int c0 = blockIdx.x * 1024;
    if (threadIdx.x < NB) cnt[threadIdx.x] = 0;
    __syncthreads();
    int gv[4], ev[4], n = 0;
    #pragma unroll
    for (int k = 0; k < 4; k++) {
        int i = c0 + k * 256 + threadIdx.x;
        if (i < M) { ev[n] = i; gv[n] = garr[i]; atomicAdd(&cnt[gv[n]], 1); n++; }
    }
    __syncthreads();
    if (threadIdx.x < NB) {
        base[threadIdx.x] = atomicAdd(&cursors[threadIdx.x], cnt[threadIdx.x]);
        cnt[threadIdx.x] = 0;
    }
    __syncthreads();
    for (int k = 0; k < n; k++) {
        int pos = base[gv[k]] + atomicAdd(&cnt[gv[k]], 1);
        perm[pos] = ev[k];
        gs[pos] = gv[k];
    }
}

// ---------------- K5: fused height + sigmoid + segment accumulate ----------
__global__ __launch_bounds__(256) void accum_kernel(
    const float* __restrict__ nh, const int* __restrict__ batch,
    const int* __restrict__ ei, const float* __restrict__ ew,
    const int* __restrict__ perm_e, const int* __restrict__ gs_e,
    const int* __restrict__ fi, const float* __restrict__ fw,
    const int* __restrict__ perm_f, const int* __restrict__ gs_f,
    const float* __restrict__ lin, float* __restrict__ out,
    int nbn, int nbe)
{
    int t = threadIdx.x & 31, sg = threadIdx.x >> 5;
    int s0 = sg * 4;
    float a0 = SCALE_C * lin[s0], a1 = SCALE_C * lin[s0 + 1],
          a2 = SCALE_C * lin[s0 + 2], a3 = SCALE_C * lin[s0 + 3];
    float acc0 = 0.f, acc1 = 0.f, acc2 = 0.f, acc3 = 0.f;
    int gcur = -1;
    float sign;
    int i0, i1, type;
    int bid = blockIdx.x;
    if (bid < nbn) {
        type = 0; i0 = bid * CH; i1 = i0 + CH; if (i1 > N_NODES) i1 = N_NODES; sign = 1.0f;
    } else if (bid < nbn + nbe) {
        type = 1; int b = bid - nbn; i0 = b * CH; i1 = i0 + CH; if (i1 > N_EDGES) i1 = N_EDGES; sign = -1.0f;
    } else {
        type = 2; int b = bid - nbn - nbe; i0 = b * CH; i1 = i0 + CH; if (i1 > N_FACES) i1 = N_FACES; sign = 1.0f;
    }

    #define FLUSH() do { if (gcur >= 0) { \
        float* o = out + gcur * (NS * NT) + s0 * NT + t; \
        atomicAdd(o,          sign * acc0); \
        atomicAdd(o + NT,     sign * acc1); \
        atomicAdd(o + 2 * NT, sign * acc2); \
        atomicAdd(o + 3 * NT, sign * acc3); \
        acc0 = acc1 = acc2 = acc3 = 0.f; } } while (0)

    if (type == 0) {
        for (int i = i0; i < i1; i++) {
            int g = batch[i];
            if (g != gcur) { FLUSH(); gcur = g; }
            float sh = SCALE_C * nh[i * NT + t];
            acc0 += sigf(a0 - sh); acc1 += sigf(a1 - sh);
            acc2 += sigf(a2 - sh); acc3 += sigf(a3 - sh);
        }
    } else if (type == 1) {
        for (int i = i0; i < i1; i++) {
            int g = gs_e[i];
            int e = perm_e[i];
            if (g != gcur) { FLUSH(); gcur = g; }
            int na = ei[e], nb = ei[N_EDGES + e];
            float h = fmaxf(nh[na * NT + t], nh[nb * NT + t]) * ew[e];
            float sh = SCALE_C * h;
            acc0 += sigf(a0 - sh); acc1 += sigf(a1 - sh);
            acc2 += sigf(a2 - sh); acc3 += sigf(a3 - sh);
        }
    } else {
        for (int i = i0; i < i1; i++) {
            int g = gs_f[i];
            int f = perm_f[i];
            if (g != gcur) { FLUSH(); gcur = g; }
            int na = fi[f], nb = fi[N_FACES + f], nc = fi[2 * N_FACES + f];
            float h = fmaxf(fmaxf(nh[na * NT + t], nh[nb * NT + t]), nh[nc * NT + t]) * fw[f];
            float sh = SCALE_C * h;
            acc0 += sigf(a0 - sh); acc1 += sigf(a1 - sh);
            acc2 += sigf(a2 - sh); acc3 += sigf(a3 - sh);
        }
    }
    FLUSH();
    #undef FLUSH
}

extern "C" void kernel_launch(void* const* d_in, const int* in_sizes, int n_in,
                              void* d_out, int out_size, void* d_ws, size_t ws_size,
                              hipStream_t stream) {
    const float* x     = (const float*)d_in[0];
    const float* nw    = (const float*)d_in[1];
    const int*   ei    = (const int*)d_in[2];
    const float* ew    = (const float*)d_in[3];
    const int*   fi    = (const int*)d_in[4];
    const float* fw    = (const float*)d_in[5];
    const int*   batch = (const int*)d_in[6];
    const float* v     = (const float*)d_in[7];
    const float* lin   = (const float*)d_in[8];
    float* out = (float*)d_out;

    char* ws = (char*)d_ws;
    // workspace layout
    int* hist_e = (int*)ws;                 // 64
    int* hist_f = hist_e + 64;              // 64
    int* cur_e  = hist_e + 128;             // 64
    int* cur_f  = hist_e + 192;             // 64
    float* nh   = (float*)(ws + 4096);                       // N*T f32 (6.4 MB)
    int* ge     = (int*)(ws + 4096 + (size_t)N_NODES * NT * 4);
    int* gf     = ge + N_EDGES;
    int* perm_e = gf + N_FACES;
    int* gs_e   = perm_e + N_EDGES;
    int* perm_f = gs_e + N_EDGES;
    int* gs_f   = perm_f + N_FACES;

    hipMemsetAsync(hist_e, 0, 256 * sizeof(int), stream);
    hipMemsetAsync(out, 0, (size_t)out_size * sizeof(float), stream);

    nh_kernel<<<(N_NODES * NT + 255) / 256, 256, 0, stream>>>(x, nw, v, nh);
    hist_kernel<<<512, 256, 0, stream>>>(ei, fi, batch, ge, gf, hist_e, hist_f);
    scan_kernel<<<1, 64, 0, stream>>>(hist_e, hist_f, cur_e, cur_f);
    scatter_kernel<<<(N_EDGES + 1023) / 1024, 256, 0, stream>>>(ge, N_EDGES, cur_e, perm_e, gs_e);
    scatter_kernel<<<(N_FACES + 1023) / 1024, 256, 0, stream>>>(gf, N_FACES, cur_f, perm_f, gs_f);

    int nbn = (N_NODES + CH - 1) / CH;
    int nbe = (N_EDGES + CH - 1) / CH;
    int nbf = (N_FACES + CH - 1) / CH;
    accum_kernel<<<nbn + nbe + nbf, 256, 0, stream>>>(
        nh, batch, ei, ew, perm_e, gs_e, fi, fw, perm_f, gs_f, lin, out, nbn, nbe);
}